// Round 3
// baseline (1073.872 us; speedup 1.0000x reference)
//
#include <hip/hip_runtime.h>
#include <hip/hip_bf16.h>

typedef __bf16 bf16_t;
typedef bf16_t bf16x8 __attribute__((ext_vector_type(8)));
typedef float  floatx4 __attribute__((ext_vector_type(4)));

constexpr int Bb = 4, Hh = 16, Nn = 2048, Dd = 64;
constexpr int BM = 128;  // queries per workgroup (8 waves)
constexpr int BN = 64;   // keys per tile
constexpr int WM = 16;   // queries per wave
constexpr int NT = Nn / BN;                          // 32 K/V tiles
constexpr float SCALE = 0.125f;                      // D^-0.5
constexpr float NEG   = -3.4028234663852886e38f;     // -FLT_MAX, matches reference

// Flash attention, bf16 MFMA (16x16x32), fp32 softmax state.
// Latency-bound fix (occupancy is register-pinned at ~16 waves/CU):
//  - double-buffered K/V LDS, one-tile-ahead register prefetch of K/V
//    (global-load latency hides under the whole tile body; vmcnt wait lands
//    at the next iteration's LDS store)
//  - ONE barrier per tile (store[cur] -> barrier -> compute[cur], buffers
//    alternate; reads of a buffer and its next overwrite are separated by
//    the intervening barrier)
//  - bias+mask prefetched one tile ahead, mask pre-folded into bias
//    (bias_pf = ok ? bias : -FLT_MAX; s*SCALE + (-FLT_MAX) rounds to
//    -FLT_MAX exactly, matching the reference where())
__global__ __launch_bounds__(512, 4)
void attn_fwd(const float* __restrict__ qg,
              const float* __restrict__ kg,
              const float* __restrict__ vg,
              const void*  __restrict__ maskg,
              const float* __restrict__ biasg,
              float* __restrict__ outg)
{
    // chunk = ((blk*2+kk)*64 + quad*16 + n); element j <-> K[key=blk*16+n][d=kk*32+quad*8+j]
    __shared__ bf16x8 k_lds[2][512];
    // chunk = ((kk*4+nblk)*64 + quad*16 + n); element j <-> V[key=kk*32+quad*8+j][d=nblk*16+n]
    __shared__ bf16x8 v_lds[2][512];
    // per-wave P: chunk = kk*64 + quad*16 + m; element j <-> P[m][key=kk*32+quad*8+j]
    __shared__ bf16x8 p_lds[8][128];

    const int tid  = threadIdx.x;
    const int wave = tid >> 6;
    const int lane = tid & 63;
    const int ln   = lane & 15;   // n (or m) within 16
    const int lq   = lane >> 4;   // quad

    const int id = blockIdx.x;    // b fastest: 4 batches sharing a bias slice run adjacently
    const int b  = id & 3;
    const int h  = (id >> 2) & 15;
    const int mt = id >> 6;       // 0..15

    // ---- mask dtype probe (wave-uniform branch) ----
    const int probe = ((const int*)maskg)[lane];
    const bool mask_i32 = __all(probe == 0 || probe == 1);
    const int*           mi = (const int*)maskg;
    const unsigned char* mb = (const unsigned char*)maskg;

    const size_t head  = (size_t)(b*Hh + h) * Nn * Dd;
    const int    qbase = mt*BM + wave*WM;

    // ---- Q A-fragments straight from global (one-time) ----
    bf16x8 qa[2];
    {
        const float* qp = qg + head + (size_t)(qbase + ln)*Dd + lq*8;
        #pragma unroll
        for (int kk = 0; kk < 2; ++kk) {
            float4 f0 = *(const float4*)(qp + kk*32);
            float4 f1 = *(const float4*)(qp + kk*32 + 4);
            bf16x8 a;
            a[0]=(bf16_t)f0.x; a[1]=(bf16_t)f0.y; a[2]=(bf16_t)f0.z; a[3]=(bf16_t)f0.w;
            a[4]=(bf16_t)f1.x; a[5]=(bf16_t)f1.y; a[6]=(bf16_t)f1.z; a[7]=(bf16_t)f1.w;
            qa[kk] = a;
        }
    }

    floatx4 o_acc[4];
    #pragma unroll
    for (int i = 0; i < 4; ++i) o_acc[i] = (floatx4){0.f,0.f,0.f,0.f};
    float mx[4], lsum[4];
    #pragma unroll
    for (int r = 0; r < 4; ++r) { mx[r] = -__builtin_inff(); lsum[r] = 0.f; }

    // staging decomposition (512 threads cover 64 keys x 64 d; 8 floats/thread each)
    const int skey = tid >> 3;
    const int sd0  = (tid & 7) * 8;
    const int sblk = skey >> 4, sn = skey & 15;          // K-side
    const int kkg  = sd0 >> 5,  qg2 = (sd0 >> 3) & 3;    // K chunk coords
    const int vkk  = skey >> 5, vq = (skey >> 3) & 3, vj = skey & 7;  // V-side
    const int vnb  = sd0 >> 4;                           // d-block constant per thread
    bf16_t* pl = (bf16_t*)p_lds[wave];

    const float* kbase = kg + head + (size_t)skey*Dd + sd0;
    const float* vbase = vg + head + (size_t)skey*Dd + sd0;

    // ---- prologue: tile-0 K/V to regs, tile-0 bias(+mask) to regs ----
    float4 kr0 = *(const float4*)(kbase);
    float4 kr1 = *(const float4*)(kbase + 4);
    float4 vr0 = *(const float4*)(vbase);
    float4 vr1 = *(const float4*)(vbase + 4);

    float bias_pf[4][4];
    {
        const size_t col0 = (size_t)ln;   // kt = 0
        #pragma unroll
        for (int r = 0; r < 4; ++r) {
            const int m = qbase + lq*4 + r;
            const size_t brow = ((size_t)h*Nn + m)*Nn + col0;
            const size_t mrow = ((size_t)b*Nn + m)*Nn + col0;
            #pragma unroll
            for (int blk = 0; blk < 4; ++blk) {
                const bool ok = mask_i32 ? (mi[mrow + blk*16] != 0)
                                         : (mb[mrow + blk*16] != 0);
                bias_pf[r][blk] = ok ? biasg[brow + blk*16] : NEG;
            }
        }
    }

    for (int kt = 0; kt < NT; ++kt) {
        const int cur = kt & 1;

        // ---- store staged regs (tile kt) -> LDS[cur] ----
        {
            bf16x8 c;
            c[0]=(bf16_t)kr0.x; c[1]=(bf16_t)kr0.y; c[2]=(bf16_t)kr0.z; c[3]=(bf16_t)kr0.w;
            c[4]=(bf16_t)kr1.x; c[5]=(bf16_t)kr1.y; c[6]=(bf16_t)kr1.z; c[7]=(bf16_t)kr1.w;
            k_lds[cur][(sblk*2 + kkg)*64 + qg2*16 + sn] = c;   // one b128 write
            float vvv[8];
            *(float4*)(vvv)   = vr0;
            *(float4*)(vvv+4) = vr1;
            bf16_t* vl = (bf16_t*)v_lds[cur];
            #pragma unroll
            for (int t = 0; t < 8; ++t) {                 // V: transposed scatter (b16 writes)
                const int nn2 = (sd0 & 8) + t;            // (sd0+t) & 15
                vl[(((vkk*4 + vnb)*64 + vq*16 + nn2) << 3) | vj] = (bf16_t)vvv[t];
            }
        }
        __syncthreads();

        // ---- issue next tile's K/V global loads (latency hides under body) ----
        if (kt + 1 < NT) {
            const float* kp = kbase + (size_t)(kt+1)*BN*Dd;
            const float* vp = vbase + (size_t)(kt+1)*BN*Dd;
            kr0 = *(const float4*)(kp);
            kr1 = *(const float4*)(kp + 4);
            vr0 = *(const float4*)(vp);
            vr1 = *(const float4*)(vp + 4);
        }

        // ---- S = Q K^T  (16m x 64keys per wave) ----
        floatx4 s_acc[4];
        #pragma unroll
        for (int i = 0; i < 4; ++i) s_acc[i] = (floatx4){0.f,0.f,0.f,0.f};
        #pragma unroll
        for (int blk = 0; blk < 4; ++blk)
            #pragma unroll
            for (int kk = 0; kk < 2; ++kk)
                s_acc[blk] = __builtin_amdgcn_mfma_f32_16x16x32_bf16(
                    qa[kk], k_lds[cur][(blk*2+kk)*64 + lane], s_acc[blk], 0, 0, 0);

        // ---- scale + (bias+mask prefolded), online softmax ----
        float rmax[4];
        #pragma unroll
        for (int r = 0; r < 4; ++r) {
            rmax[r] = NEG;
            #pragma unroll
            for (int blk = 0; blk < 4; ++blk) {
                // masked: s*SCALE + (-FLT_MAX) rounds to -FLT_MAX exactly
                const float val = s_acc[blk][r]*SCALE + bias_pf[r][blk];
                s_acc[blk][r] = val;
                rmax[r] = fmaxf(rmax[r], val);
            }
        }
        #pragma unroll
        for (int off = 1; off < 16; off <<= 1)
            #pragma unroll
            for (int r = 0; r < 4; ++r)
                rmax[r] = fmaxf(rmax[r], __shfl_xor(rmax[r], off, 64));

        float alph[4], rsum[4];
        #pragma unroll
        for (int r = 0; r < 4; ++r) {
            const float mnew = fmaxf(mx[r], rmax[r]);
            alph[r] = __expf(mx[r] - mnew);
            mx[r] = mnew;
            const int m = lq*4 + r;
            float s = 0.f;
            #pragma unroll
            for (int blk = 0; blk < 4; ++blk) {
                const bf16_t p = (bf16_t)__expf(s_acc[blk][r] - mnew);
                s += (float)p;   // sum the bf16-rounded p: num/denom stay consistent
                const int key = blk*16 + ln;
                const int kk2 = key >> 5, q2 = (key >> 3) & 3, j2 = key & 7;
                pl[((kk2*64 + q2*16 + m) << 3) | j2] = p;   // P -> LDS inline
            }
            rsum[r] = s;
        }
        #pragma unroll
        for (int off = 1; off < 16; off <<= 1)
            #pragma unroll
            for (int r = 0; r < 4; ++r)
                rsum[r] += __shfl_xor(rsum[r], off, 64);
        #pragma unroll
        for (int r = 0; r < 4; ++r) {
            lsum[r] = lsum[r]*alph[r] + rsum[r];
            #pragma unroll
            for (int nb = 0; nb < 4; ++nb)
                o_acc[nb][r] *= alph[r];
        }

        // ---- prefetch next tile's bias(+mask) into regs ----
        if (kt + 1 < NT) {
            const size_t col0 = (size_t)(kt+1)*BN + ln;
            #pragma unroll
            for (int r = 0; r < 4; ++r) {
                const int m = qbase + lq*4 + r;
                const size_t brow = ((size_t)h*Nn + m)*Nn + col0;
                const size_t mrow = ((size_t)b*Nn + m)*Nn + col0;
                #pragma unroll
                for (int blk = 0; blk < 4; ++blk) {
                    const bool ok = mask_i32 ? (mi[mrow + blk*16] != 0)
                                             : (mb[mrow + blk*16] != 0);
                    bias_pf[r][blk] = ok ? biasg[brow + blk*16] : NEG;
                }
            }
        }

        // ---- O += P V  (p_lds is per-wave: same-wave write->read needs no barrier) ----
        #pragma unroll
        for (int kk = 0; kk < 2; ++kk) {
            const bf16x8 pa = p_lds[wave][kk*64 + lane];
            #pragma unroll
            for (int nb = 0; nb < 4; ++nb)
                o_acc[nb] = __builtin_amdgcn_mfma_f32_16x16x32_bf16(
                    pa, v_lds[cur][(kk*4+nb)*64 + lane], o_acc[nb], 0, 0, 0);
        }
    }

    // ---- epilogue: O / l ----
    #pragma unroll
    for (int r = 0; r < 4; ++r) {
        const int m = qbase + lq*4 + r;
        const float inv = 1.f / lsum[r];
        float* op = outg + head + (size_t)m*Dd + ln;
        #pragma unroll
        for (int nb = 0; nb < 4; ++nb)
            op[nb*16] = o_acc[nb][r] * inv;
    }
}

extern "C" void kernel_launch(void* const* d_in, const int* in_sizes, int n_in,
                              void* d_out, int out_size, void* d_ws, size_t ws_size,
                              hipStream_t stream) {
    const float* q    = (const float*)d_in[0];
    const float* k    = (const float*)d_in[1];
    const float* v    = (const float*)d_in[2];
    const void*  mask = d_in[3];
    const float* bias = (const float*)d_in[4];
    float* out = (float*)d_out;
    (void)in_sizes; (void)n_in; (void)out_size; (void)d_ws; (void)ws_size;

    const int grid = Bb * Hh * (Nn / BM);   // 1024
    attn_fwd<<<grid, 512, 0, stream>>>(q, k, v, mask, bias, out);
}